// Round 4
// baseline (105.677 us; speedup 1.0000x reference)
//
#include <hip/hip_runtime.h>

#define NN 512          // nodes
#define IND 512         // in features
#define NH 8            // heads
#define NF 64           // hidden per head

// ---------------------------------------------------------------------------
// K1: fused NT GEMM (no pre-transpose): C[r][c] = sum_k A[r][k] * B[c][k]
//   z=0: A=Ws, B=X  -> C = Gs_t [o][n]
//   z=1: A=X,  B=Wt -> C = Gt   [n][o]
// Block: 16 r x 128 c, 512 thr = 8 waves = 4 row-groups x 2 k-halves
// (split-K in block). BR=16: B-panel feed 32 B/cyc/CU vs ~56 L2 ceiling
// -> compute-bound. LDS double-buffered, ONE barrier per chunk; next chunk's
// global loads issued before the barrier, LDS writes after the compute, so
// L2 latency hides under the 1024-cyc chunk compute.
// Grid: (4, 32, 2) = 256 blocks = 1/CU.  [proven -3.8us in round 3: frozen]
// ---------------------------------------------------------------------------
__global__ __launch_bounds__(512) void gemm_nt(
    const float* __restrict__ Aa, const float* __restrict__ Ba, float* __restrict__ Ca,
    const float* __restrict__ Ab, const float* __restrict__ Bb, float* __restrict__ Cb)
{
    const float* A = blockIdx.z ? Ab : Aa;
    const float* B = blockIdx.z ? Bb : Ba;
    float*       C = blockIdx.z ? Cb : Ca;

    // pitch 132: write lanes are c-contiguous at fixed k -> <=4-way;
    // float2 reads at c=2*lane -> 2-way (free on gfx950).
    __shared__ __align__(16) float Vs[2][2][32][132];   // [dbuf][kh][k][c]
    __shared__ float2 sp[4][4][64];

    const int tid  = threadIdx.x;
    const int wv   = __builtin_amdgcn_readfirstlane(tid >> 6);
    const int lane = tid & 63;
    const int rg = wv & 3, kh = wv >> 2;
    const int r0 = blockIdx.y * 16 + rg * 4;
    const int c0 = blockIdx.x * 128;

    const float* Sp = A + (size_t)r0 * IND + kh * 256;

    // staging: 256 threads per k-half stage 128 c x 32 k per chunk;
    // 2 threads per column, 16 k (4 x float4 = 64B contiguous) each.
    const int ts = tid & 255;
    const int sc = ts & 127;
    const int kq = ts >> 7;
    const float* Brow = B + (size_t)(c0 + sc) * IND + kh * 256 + kq * 16;

    float2 a0 = {0.f,0.f}, a1 = {0.f,0.f}, a2 = {0.f,0.f}, a3 = {0.f,0.f};

    // ---- prologue: stage chunk 0 into buf 0
    float4 f[4];
    {
        const float4* bp = reinterpret_cast<const float4*>(Brow);
        #pragma unroll
        for (int i = 0; i < 4; ++i) f[i] = bp[i];
        #pragma unroll
        for (int i = 0; i < 4; ++i) {
            Vs[0][kh][kq * 16 + i * 4 + 0][sc] = f[i].x;
            Vs[0][kh][kq * 16 + i * 4 + 1][sc] = f[i].y;
            Vs[0][kh][kq * 16 + i * 4 + 2][sc] = f[i].z;
            Vs[0][kh][kq * 16 + i * 4 + 3][sc] = f[i].w;
        }
    }

    for (int ch = 0; ch < 8; ++ch) {
        // ---- issue next chunk's global loads (latency hides under compute)
        if (ch < 7) {
            const float4* bp = reinterpret_cast<const float4*>(Brow + (ch + 1) * 32);
            #pragma unroll
            for (int i = 0; i < 4; ++i) f[i] = bp[i];
        }
        __syncthreads();              // buf[ch&1] fully written; buf[(ch+1)&1] fully drained
        const float* Spc = Sp + ch * 32;
        const float (*V)[132] = Vs[ch & 1][kh];
        #pragma unroll 8
        for (int kk = 0; kk < 32; ++kk) {
            float2 v = *reinterpret_cast<const float2*>(&V[kk][lane * 2]);
            float s0 = Spc[kk];
            float s1 = Spc[IND + kk];
            float s2 = Spc[2 * IND + kk];
            float s3 = Spc[3 * IND + kk];
            a0.x = fmaf(s0, v.x, a0.x); a0.y = fmaf(s0, v.y, a0.y);
            a1.x = fmaf(s1, v.x, a1.x); a1.y = fmaf(s1, v.y, a1.y);
            a2.x = fmaf(s2, v.x, a2.x); a2.y = fmaf(s2, v.y, a2.y);
            a3.x = fmaf(s3, v.x, a3.x); a3.y = fmaf(s3, v.y, a3.y);
        }
        // ---- write next chunk (other buffer; safe: all waves passed the
        //      barrier above, hence finished reading it in iter ch-1)
        if (ch < 7) {
            #pragma unroll
            for (int i = 0; i < 4; ++i) {
                Vs[(ch + 1) & 1][kh][kq * 16 + i * 4 + 0][sc] = f[i].x;
                Vs[(ch + 1) & 1][kh][kq * 16 + i * 4 + 1][sc] = f[i].y;
                Vs[(ch + 1) & 1][kh][kq * 16 + i * 4 + 2][sc] = f[i].z;
                Vs[(ch + 1) & 1][kh][kq * 16 + i * 4 + 3][sc] = f[i].w;
            }
        }
    }

    // ---- split-K reduce + store (kh=1 exchanges via LDS, kh=0 writes C)
    if (kh) {
        sp[rg][0][lane] = a0; sp[rg][1][lane] = a1;
        sp[rg][2][lane] = a2; sp[rg][3][lane] = a3;
    }
    __syncthreads();
    if (!kh) {
        float2 p;
        const int cc = c0 + lane * 2;
        p = sp[rg][0][lane]; a0.x += p.x; a0.y += p.y;
        p = sp[rg][1][lane]; a1.x += p.x; a1.y += p.y;
        p = sp[rg][2][lane]; a2.x += p.x; a2.y += p.y;
        p = sp[rg][3][lane]; a3.x += p.x; a3.y += p.y;
        *reinterpret_cast<float2*>(C + (size_t)(r0 + 0) * NN + cc) = a0;
        *reinterpret_cast<float2*>(C + (size_t)(r0 + 1) * NN + cc) = a1;
        *reinterpret_cast<float2*>(C + (size_t)(r0 + 2) * NN + cc) = a2;
        *reinterpret_cast<float2*>(C + (size_t)(r0 + 3) * NN + cc) = a3;
    }
}

// ---------------------------------------------------------------------------
// K2: per (i-tile of 8, head h) block, 512 threads (8 waves).
//   Round-4 scheduling-only changes (no semantic change):
//   - launch_bounds(512,6): VGPR cap ~84 (audit: ~55 live max) -> >=3
//     blocks/CU so phases of different blocks interleave across barriers.
//   - adj loads prefetched to the TOP of phase 1 (L2 latency hides under
//     the 64-f VALU loop instead of serializing at its tail).
//   - g-stream software pipelined one f ahead.
//   phase 1: scores = 0.6*P_j + 0.4*sum_f a_f*|gs_jf + gt_if|  (Q_i term
//            softmax-invariant, dropped). 2 VALU/elem = floor.
//   phase 2: softmax (one wave per row); direct scatter to out_att[i][j][h]
//            (h-blocks sharing a line land on the same XCD -> L2 merges).
//   phase 3: head_output = att @ Gt; waves split j; b128 att broadcasts.
// ---------------------------------------------------------------------------
__global__ __launch_bounds__(512, 6) void gat_attn(
    const float* __restrict__ Gs_t,      // [512 (h*64+f)][512 j]
    const float* __restrict__ Gt,        // [512 n][512 (h*64+f)]
    const float* __restrict__ attn_w,    // [64]
    const int*   __restrict__ adj,       // [512][512]
    float* __restrict__ out_feat,        // [512][512]
    float* __restrict__ out_att)         // [512][512][8]
{
    __shared__ float s_sc[8][512];
    __shared__ float s_red[8][8][64];

    const int tid = threadIdx.x;
    const int i0  = blockIdx.x * 8;
    const int h   = blockIdx.y;

    // ---- phase 1: scores (one j per thread, 8 i's) ----
    {
        const int j = tid;
        // prefetch adjacency early: consumed only after the f-loop
        int ad[8];
        #pragma unroll
        for (int i = 0; i < 8; ++i) ad[i] = adj[(size_t)(i0 + i) * NN + j];

        float acc[8];
        #pragma unroll
        for (int i = 0; i < 8; ++i) acc[i] = 0.f;
        float p = 0.f;                              // sum_f a_f * gs_jf
        const float* gsp = Gs_t + (size_t)h * NF * NN + j;
        const float* gtp = Gt + (size_t)i0 * IND + h * NF;
        float g = gsp[0];                           // pipeline head
        #pragma unroll 4
        for (int f = 0; f < NF; ++f) {
            float gn = (f < NF - 1) ? gsp[(size_t)(f + 1) * NN] : 0.f;
            float w = attn_w[f];                    // uniform -> s_load
            p = fmaf(w, g, p);
            #pragma unroll
            for (int i = 0; i < 8; ++i) {
                float t = g + gtp[(size_t)i * IND + f];  // uniform -> s_load
                acc[i] = fmaf(w, fabsf(t), acc[i]);
            }
            g = gn;
        }
        const float px = 0.6f * p;
        #pragma unroll
        for (int i = 0; i < 8; ++i)
            s_sc[i][j] = ad[i] ? fmaf(0.4f, acc[i], px) : -INFINITY;
    }
    __syncthreads();

    // ---- phase 2: softmax (one wave per row) + direct attention scatter ----
    {
        const int w = tid >> 6, lane = tid & 63;
        float m = -INFINITY;
        #pragma unroll
        for (int r = 0; r < 8; ++r) m = fmaxf(m, s_sc[w][lane + r * 64]);
        #pragma unroll
        for (int off = 32; off >= 1; off >>= 1) m = fmaxf(m, __shfl_xor(m, off, 64));
        float e[8];
        float sum = 0.f;
        #pragma unroll
        for (int r = 0; r < 8; ++r) {
            float ev = __expf(s_sc[w][lane + r * 64] - m);
            e[r] = ev;
            sum += ev;
        }
        #pragma unroll
        for (int off = 32; off >= 1; off >>= 1) sum += __shfl_xor(sum, off, 64);
        float inv = 1.f / sum;
        const int i = i0 + w;
        #pragma unroll
        for (int r = 0; r < 8; ++r) {
            int j = lane + r * 64;
            float a = e[r] * inv;
            s_sc[w][j] = a;
            out_att[((size_t)i * NN + j) * NH + h] = a;
        }
    }
    __syncthreads();

    // ---- phase 3: head_output = att @ Gt (waves split j 64-wide) ----
    {
        const int w = tid >> 6, lane = tid & 63;
        const int jb = w * 64;
        float o[8];
        #pragma unroll
        for (int i = 0; i < 8; ++i) o[i] = 0.f;
        const float* gtc = Gt + h * NF + lane;
        #pragma unroll 2
        for (int s = 0; s < 16; ++s) {
            const int j = jb + 4 * s;
            float4 b[8];
            #pragma unroll
            for (int i = 0; i < 8; ++i)
                b[i] = *reinterpret_cast<const float4*>(&s_sc[i][j]);
            float gv;
            gv = gtc[(size_t)(j + 0) * IND];
            #pragma unroll
            for (int i = 0; i < 8; ++i) o[i] = fmaf(b[i].x, gv, o[i]);
            gv = gtc[(size_t)(j + 1) * IND];
            #pragma unroll
            for (int i = 0; i < 8; ++i) o[i] = fmaf(b[i].y, gv, o[i]);
            gv = gtc[(size_t)(j + 2) * IND];
            #pragma unroll
            for (int i = 0; i < 8; ++i) o[i] = fmaf(b[i].z, gv, o[i]);
            gv = gtc[(size_t)(j + 3) * IND];
            #pragma unroll
            for (int i = 0; i < 8; ++i) o[i] = fmaf(b[i].w, gv, o[i]);
        }
        #pragma unroll
        for (int i = 0; i < 8; ++i) s_red[w][i][lane] = o[i];
    }
    __syncthreads();
    {
        const int ii = tid >> 6, f = tid & 63;
        float s = 0.f;
        #pragma unroll
        for (int w = 0; w < 8; ++w) s += s_red[w][ii][f];
        out_feat[(size_t)(i0 + ii) * (NH * NF) + h * NF + f] = s;
    }
}

extern "C" void kernel_launch(void* const* d_in, const int* in_sizes, int n_in,
                              void* d_out, int out_size, void* d_ws, size_t ws_size,
                              hipStream_t stream) {
    const float* X   = (const float*)d_in[0];   // h [1,512,512]
    const float* Ws  = (const float*)d_in[1];   // W_source [512,512]
    const float* Wtg = (const float*)d_in[2];   // W_target [512,512]
    const float* aw  = (const float*)d_in[3];   // attn_w [64]
    const int*   adj = (const int*)d_in[4];     // adjacency [512,512,1]

    float* Gs_t = (float*)d_ws;                 // [512 o][512 n]
    float* Gt   = Gs_t + (size_t)NN * IND;      // [512 n][512 o]

    float* out_feat = (float*)d_out;                    // [512,512]
    float* out_att  = out_feat + (size_t)NN * NH * NF;  // [512,512,8]

    // K1: z=0: Gs_t = Ws . X^T ; z=1: Gt = X . Wt^T   (transpose fused via LDS)
    hipLaunchKernelGGL(gemm_nt, dim3(4, 32, 2), dim3(512), 0, stream,
                       Ws, X, Gs_t, X, Wtg, Gt);
    hipLaunchKernelGGL(gat_attn, dim3(NN / 8, NH), dim3(512), 0, stream,
                       Gs_t, Gt, aw, adj, out_feat, out_att);
}

// Round 5
// 103.327 us; speedup vs baseline: 1.0227x; 1.0227x over previous
//
#include <hip/hip_runtime.h>

#define NN 512          // nodes
#define IND 512         // in features
#define NH 8            // heads
#define NF 64           // hidden per head

// ---------------------------------------------------------------------------
// K1: fused NT GEMM (no pre-transpose): C[r][c] = sum_k A[r][k] * B[c][k]
//   z=0: A=Ws, B=X  -> C = Gs_t [o][n]
//   z=1: A=X,  B=Wt -> C = Gt   [n][o]
// Block: 16 r x 128 c, 512 thr = 8 waves = 4 row-groups x 2 k-halves
// (split-K in block). BR=16: B-panel feed 32 B/cyc/CU vs ~56 L2 ceiling
// -> compute-bound. LDS double-buffered, ONE barrier per chunk; next chunk's
// global loads issued before the barrier, LDS writes after the compute, so
// L2 latency hides under the 1024-cyc chunk compute.
// Grid: (4, 32, 2) = 256 blocks = 1/CU.  [proven -3.8us in round 3: FROZEN]
// ---------------------------------------------------------------------------
__global__ __launch_bounds__(512) void gemm_nt(
    const float* __restrict__ Aa, const float* __restrict__ Ba, float* __restrict__ Ca,
    const float* __restrict__ Ab, const float* __restrict__ Bb, float* __restrict__ Cb)
{
    const float* A = blockIdx.z ? Ab : Aa;
    const float* B = blockIdx.z ? Bb : Ba;
    float*       C = blockIdx.z ? Cb : Ca;

    // pitch 132: write lanes are c-contiguous at fixed k -> <=4-way;
    // float2 reads at c=2*lane -> 2-way (free on gfx950).
    __shared__ __align__(16) float Vs[2][2][32][132];   // [dbuf][kh][k][c]
    __shared__ float2 sp[4][4][64];

    const int tid  = threadIdx.x;
    const int wv   = __builtin_amdgcn_readfirstlane(tid >> 6);
    const int lane = tid & 63;
    const int rg = wv & 3, kh = wv >> 2;
    const int r0 = blockIdx.y * 16 + rg * 4;
    const int c0 = blockIdx.x * 128;

    const float* Sp = A + (size_t)r0 * IND + kh * 256;

    // staging: 256 threads per k-half stage 128 c x 32 k per chunk;
    // 2 threads per column, 16 k (4 x float4 = 64B contiguous) each.
    const int ts = tid & 255;
    const int sc = ts & 127;
    const int kq = ts >> 7;
    const float* Brow = B + (size_t)(c0 + sc) * IND + kh * 256 + kq * 16;

    float2 a0 = {0.f,0.f}, a1 = {0.f,0.f}, a2 = {0.f,0.f}, a3 = {0.f,0.f};

    // ---- prologue: stage chunk 0 into buf 0
    float4 f[4];
    {
        const float4* bp = reinterpret_cast<const float4*>(Brow);
        #pragma unroll
        for (int i = 0; i < 4; ++i) f[i] = bp[i];
        #pragma unroll
        for (int i = 0; i < 4; ++i) {
            Vs[0][kh][kq * 16 + i * 4 + 0][sc] = f[i].x;
            Vs[0][kh][kq * 16 + i * 4 + 1][sc] = f[i].y;
            Vs[0][kh][kq * 16 + i * 4 + 2][sc] = f[i].z;
            Vs[0][kh][kq * 16 + i * 4 + 3][sc] = f[i].w;
        }
    }

    for (int ch = 0; ch < 8; ++ch) {
        // ---- issue next chunk's global loads (latency hides under compute)
        if (ch < 7) {
            const float4* bp = reinterpret_cast<const float4*>(Brow + (ch + 1) * 32);
            #pragma unroll
            for (int i = 0; i < 4; ++i) f[i] = bp[i];
        }
        __syncthreads();              // buf[ch&1] fully written; buf[(ch+1)&1] fully drained
        const float* Spc = Sp + ch * 32;
        const float (*V)[132] = Vs[ch & 1][kh];
        #pragma unroll 8
        for (int kk = 0; kk < 32; ++kk) {
            float2 v = *reinterpret_cast<const float2*>(&V[kk][lane * 2]);
            float s0 = Spc[kk];
            float s1 = Spc[IND + kk];
            float s2 = Spc[2 * IND + kk];
            float s3 = Spc[3 * IND + kk];
            a0.x = fmaf(s0, v.x, a0.x); a0.y = fmaf(s0, v.y, a0.y);
            a1.x = fmaf(s1, v.x, a1.x); a1.y = fmaf(s1, v.y, a1.y);
            a2.x = fmaf(s2, v.x, a2.x); a2.y = fmaf(s2, v.y, a2.y);
            a3.x = fmaf(s3, v.x, a3.x); a3.y = fmaf(s3, v.y, a3.y);
        }
        // ---- write next chunk (other buffer; safe: all waves passed the
        //      barrier above, hence finished reading it in iter ch-1)
        if (ch < 7) {
            #pragma unroll
            for (int i = 0; i < 4; ++i) {
                Vs[(ch + 1) & 1][kh][kq * 16 + i * 4 + 0][sc] = f[i].x;
                Vs[(ch + 1) & 1][kh][kq * 16 + i * 4 + 1][sc] = f[i].y;
                Vs[(ch + 1) & 1][kh][kq * 16 + i * 4 + 2][sc] = f[i].z;
                Vs[(ch + 1) & 1][kh][kq * 16 + i * 4 + 3][sc] = f[i].w;
            }
        }
    }

    // ---- split-K reduce + store (kh=1 exchanges via LDS, kh=0 writes C)
    if (kh) {
        sp[rg][0][lane] = a0; sp[rg][1][lane] = a1;
        sp[rg][2][lane] = a2; sp[rg][3][lane] = a3;
    }
    __syncthreads();
    if (!kh) {
        float2 p;
        const int cc = c0 + lane * 2;
        p = sp[rg][0][lane]; a0.x += p.x; a0.y += p.y;
        p = sp[rg][1][lane]; a1.x += p.x; a1.y += p.y;
        p = sp[rg][2][lane]; a2.x += p.x; a2.y += p.y;
        p = sp[rg][3][lane]; a3.x += p.x; a3.y += p.y;
        *reinterpret_cast<float2*>(C + (size_t)(r0 + 0) * NN + cc) = a0;
        *reinterpret_cast<float2*>(C + (size_t)(r0 + 1) * NN + cc) = a1;
        *reinterpret_cast<float2*>(C + (size_t)(r0 + 2) * NN + cc) = a2;
        *reinterpret_cast<float2*>(C + (size_t)(r0 + 3) * NN + cc) = a3;
    }
}

// ---------------------------------------------------------------------------
// K2: per (i-tile of 8, head h) block, 512 threads (8 waves).
//   EXACT round-3 version (103.36us) — round 4's scheduling experiments
//   (launch_bounds cap, adj prefetch, g-pipeline) regressed +2.3us and are
//   reverted: the compiler's own schedule is the proven optimum here.
//   phase 1: scores = 0.6*P_j + 0.4*sum_f a_f*|gs_jf + gt_if|  (Q_i term is
//            softmax-invariant and dropped). One j per thread, 8 i's;
//            2 VALU/element (v_add + v_fma with abs modifier) = floor.
//   phase 2: softmax, one wave per row; direct scatter to out_att[i][j][h]
//            (the 8 h-blocks sharing a line are 64 apart in linear bid ->
//            same XCD -> partial-line writes combine in that XCD's L2).
//   phase 3: head_output = att @ Gt; waves split j; uniform ds_read_b128
//            broadcasts of att rows (broadcast = conflict-free).
// ---------------------------------------------------------------------------
__global__ __launch_bounds__(512) void gat_attn(
    const float* __restrict__ Gs_t,      // [512 (h*64+f)][512 j]
    const float* __restrict__ Gt,        // [512 n][512 (h*64+f)]
    const float* __restrict__ attn_w,    // [64]
    const int*   __restrict__ adj,       // [512][512]
    float* __restrict__ out_feat,        // [512][512]
    float* __restrict__ out_att)         // [512][512][8]
{
    __shared__ float s_sc[8][512];
    __shared__ float s_red[8][8][64];

    const int tid = threadIdx.x;
    const int i0  = blockIdx.x * 8;
    const int h   = blockIdx.y;

    // ---- phase 1: scores (one j per thread, 8 i's) ----
    {
        const int j = tid;
        float acc[8];
        #pragma unroll
        for (int i = 0; i < 8; ++i) acc[i] = 0.f;
        float p = 0.f;                              // sum_f a_f * gs_jf
        const float* gsp = Gs_t + (size_t)h * NF * NN + j;
        const float* gtp = Gt + (size_t)i0 * IND + h * NF;
        #pragma unroll 4
        for (int f = 0; f < NF; ++f) {
            float w = attn_w[f];                    // uniform -> s_load
            float g = gsp[(size_t)f * NN];          // coalesced 256B/wave
            p = fmaf(w, g, p);
            #pragma unroll
            for (int i = 0; i < 8; ++i) {
                float t = g + gtp[(size_t)i * IND + f];  // uniform -> s_load
                acc[i] = fmaf(w, fabsf(t), acc[i]);
            }
        }
        const float px = 0.6f * p;
        #pragma unroll
        for (int i = 0; i < 8; ++i) {
            int ad = adj[(size_t)(i0 + i) * NN + j];
            s_sc[i][j] = ad ? fmaf(0.4f, acc[i], px) : -INFINITY;
        }
    }
    __syncthreads();

    // ---- phase 2: softmax (one wave per row) + direct attention scatter ----
    {
        const int w = tid >> 6, lane = tid & 63;
        float m = -INFINITY;
        #pragma unroll
        for (int r = 0; r < 8; ++r) m = fmaxf(m, s_sc[w][lane + r * 64]);
        #pragma unroll
        for (int off = 32; off >= 1; off >>= 1) m = fmaxf(m, __shfl_xor(m, off, 64));
        float e[8];
        float sum = 0.f;
        #pragma unroll
        for (int r = 0; r < 8; ++r) {
            float ev = __expf(s_sc[w][lane + r * 64] - m);
            e[r] = ev;
            sum += ev;
        }
        #pragma unroll
        for (int off = 32; off >= 1; off >>= 1) sum += __shfl_xor(sum, off, 64);
        float inv = 1.f / sum;
        const int i = i0 + w;
        #pragma unroll
        for (int r = 0; r < 8; ++r) {
            int j = lane + r * 64;
            float a = e[r] * inv;
            s_sc[w][j] = a;
            out_att[((size_t)i * NN + j) * NH + h] = a;
        }
    }
    __syncthreads();

    // ---- phase 3: head_output = att @ Gt (waves split j 64-wide) ----
    {
        const int w = tid >> 6, lane = tid & 63;
        const int jb = w * 64;
        float o[8];
        #pragma unroll
        for (int i = 0; i < 8; ++i) o[i] = 0.f;
        const float* gtc = Gt + h * NF + lane;
        #pragma unroll 2
        for (int s = 0; s < 16; ++s) {
            const int j = jb + 4 * s;
            float4 b[8];
            #pragma unroll
            for (int i = 0; i < 8; ++i)
                b[i] = *reinterpret_cast<const float4*>(&s_sc[i][j]);
            float gv;
            gv = gtc[(size_t)(j + 0) * IND];
            #pragma unroll
            for (int i = 0; i < 8; ++i) o[i] = fmaf(b[i].x, gv, o[i]);
            gv = gtc[(size_t)(j + 1) * IND];
            #pragma unroll
            for (int i = 0; i < 8; ++i) o[i] = fmaf(b[i].y, gv, o[i]);
            gv = gtc[(size_t)(j + 2) * IND];
            #pragma unroll
            for (int i = 0; i < 8; ++i) o[i] = fmaf(b[i].z, gv, o[i]);
            gv = gtc[(size_t)(j + 3) * IND];
            #pragma unroll
            for (int i = 0; i < 8; ++i) o[i] = fmaf(b[i].w, gv, o[i]);
        }
        #pragma unroll
        for (int i = 0; i < 8; ++i) s_red[w][i][lane] = o[i];
    }
    __syncthreads();
    {
        const int ii = tid >> 6, f = tid & 63;
        float s = 0.f;
        #pragma unroll
        for (int w = 0; w < 8; ++w) s += s_red[w][ii][f];
        out_feat[(size_t)(i0 + ii) * (NH * NF) + h * NF + f] = s;
    }
}

extern "C" void kernel_launch(void* const* d_in, const int* in_sizes, int n_in,
                              void* d_out, int out_size, void* d_ws, size_t ws_size,
                              hipStream_t stream) {
    const float* X   = (const float*)d_in[0];   // h [1,512,512]
    const float* Ws  = (const float*)d_in[1];   // W_source [512,512]
    const float* Wtg = (const float*)d_in[2];   // W_target [512,512]
    const float* aw  = (const float*)d_in[3];   // attn_w [64]
    const int*   adj = (const int*)d_in[4];     // adjacency [512,512,1]

    float* Gs_t = (float*)d_ws;                 // [512 o][512 n]
    float* Gt   = Gs_t + (size_t)NN * IND;      // [512 n][512 o]

    float* out_feat = (float*)d_out;                    // [512,512]
    float* out_att  = out_feat + (size_t)NN * NH * NF;  // [512,512,8]

    // K1: z=0: Gs_t = Ws . X^T ; z=1: Gt = X . Wt^T   (transpose fused via LDS)
    hipLaunchKernelGGL(gemm_nt, dim3(4, 32, 2), dim3(512), 0, stream,
                       Ws, X, Gs_t, X, Wtg, Gt);
    hipLaunchKernelGGL(gat_attn, dim3(NN / 8, NH), dim3(512), 0, stream,
                       Gs_t, Gt, aw, adj, out_feat, out_att);
}